// Round 13
// baseline (3162.297 us; speedup 1.0000x reference)
//
#include <hip/hip_runtime.h>
#include <hip/hip_bf16.h>

typedef unsigned short u16;
typedef unsigned int u32;
typedef __attribute__((ext_vector_type(8))) short bf16x8;
typedef __attribute__((ext_vector_type(4))) float f32x4;

#define GLDS(gptr, lptr) __builtin_amdgcn_global_load_lds( \
    (const __attribute__((address_space(1))) u32*)(gptr), \
    (__attribute__((address_space(3))) u32*)(lptr), 16, 0, 0)

__device__ __forceinline__ float bf2f(u16 x) {
  union { float f; u32 u; } c; c.u = ((u32)x) << 16; return c.f;
}
__device__ __forceinline__ u16 f2bf(float f) {
  union { float f; u32 u; } c; c.f = f;
  u32 u = c.u;
  return (u16)((u + 0x7FFFu + ((u >> 16) & 1u)) >> 16);
}
__device__ __forceinline__ uint2 pack_bf4(f32x4 v) {
  uint2 pk;
  pk.x = ((u32)f2bf(v[1]) << 16) | (u32)f2bf(v[0]);
  pk.y = ((u32)f2bf(v[3]) << 16) | (u32)f2bf(v[2]);
  return pk;
}
__device__ __forceinline__ f32x4 unpack_bf4(uint2 pk) {
  f32x4 v;
  v[0] = bf2f((u16)(pk.x & 0xFFFF));
  v[1] = bf2f((u16)(pk.x >> 16));
  v[2] = bf2f((u16)(pk.y & 0xFFFF));
  v[3] = bf2f((u16)(pk.y >> 16));
  return v;
}
__device__ __forceinline__ float gelu1(float v) {
  float t = 0.7978845608028654f * (v + 0.044715f * v * v * v);
  t = fminf(fmaxf(t, -15.f), 15.f);
  float e = __expf(2.f * t);
  return 0.5f * v * (1.f + (e - 1.f) / (e + 1.f));
}

// ---------------------------------------------------------------------------
// 128x128, BK=64 2-phase GEMM — 256 threads / 4 waves (2x2), per-wave 64x64.
// (Best measured config; R8 counted-vmcnt, R11 8-wave, R2/R5 4-phase all
// null/negative — this is the structure plateau at ~650 TF for K=768.)
// EPI: 0 = fp32 store, 1 = bf16 store, 2 = gelu->bf16,
//      3 = gated residual into BF16 xres, 4 = fp32 non-temporal store
// ---------------------------------------------------------------------------
template<int EPI>
__global__ __launch_bounds__(256)
void gemm64_kernel(const u16* __restrict__ A, const u16* __restrict__ Bt,
                   const float* __restrict__ bias,
                   u16* __restrict__ outb, float* __restrict__ outf,
                   u16* __restrict__ xres, const float* __restrict__ gate, int gstride,
                   int M, int N, int K)
{
  __shared__ u16 ldsA[2][128 * 64];
  __shared__ u16 ldsB[2][128 * 64];
  const int tid = threadIdx.x;
  const int m0 = blockIdx.y << 7;
  const int n0 = blockIdx.x << 7;

  const int wid = tid >> 6, lane = tid & 63;
  const int wm = wid >> 1, wn = wid & 1;
  const int lr = lane & 15, lg = lane >> 4;

  f32x4 acc[4][4];
  #pragma unroll
  for (int i = 0; i < 4; ++i)
    #pragma unroll
    for (int j = 0; j < 4; ++j)
      acc[i][j] = (f32x4){0.f, 0.f, 0.f, 0.f};

  const int KT = K >> 6;
  int cur = 0;

  #define STAGE64(buf, kt) do { \
    int k0_ = (kt) << 6; \
    _Pragma("unroll") \
    for (int iss = 0; iss < 4; ++iss) { \
      int f_ = iss * 256 + tid; \
      int row_ = f_ >> 3, gl_ = f_ & 7; \
      int g_ = gl_ ^ (row_ & 7); \
      GLDS(A + (size_t)(m0 + row_) * K + k0_ + g_ * 8, &ldsA[buf][f_ * 8]); \
      GLDS(Bt + (size_t)(n0 + row_) * K + k0_ + g_ * 8, &ldsB[buf][f_ * 8]); \
    } \
  } while (0)

  STAGE64(0, 0);
  __syncthreads();
  for (int kt = 0; kt < KT; ++kt) {
    if (kt + 1 < KT) STAGE64(cur ^ 1, kt + 1);
    #pragma unroll
    for (int kk = 0; kk < 2; ++kk) {
      bf16x8 af[4], bv[4];
      #pragma unroll
      for (int i = 0; i < 4; ++i) {
        int ra = wm * 64 + i * 16 + lr;
        int da = kk * 4 + lg;
        af[i] = *(const bf16x8*)&ldsA[cur][(ra * 8 + (da ^ (ra & 7))) * 8];
        int rb = wn * 64 + i * 16 + lr;
        bv[i] = *(const bf16x8*)&ldsB[cur][(rb * 8 + (da ^ (rb & 7))) * 8];
      }
      #pragma unroll
      for (int mi = 0; mi < 4; ++mi)
        #pragma unroll
        for (int ni = 0; ni < 4; ++ni)
          acc[mi][ni] = __builtin_amdgcn_mfma_f32_16x16x32_bf16(bv[ni], af[mi], acc[mi][ni], 0, 0, 0);
    }
    __syncthreads();
    cur ^= 1;
  }
  #undef STAGE64

  f32x4 b4[4];
  #pragma unroll
  for (int ni = 0; ni < 4; ++ni)
    b4[ni] = *(const f32x4*)&bias[n0 + wn * 64 + ni * 16 + lg * 4];

  #pragma unroll
  for (int mi = 0; mi < 4; ++mi) {
    int row = m0 + wm * 64 + mi * 16 + lr;
    int bb = row / 100;
    #pragma unroll
    for (int ni = 0; ni < 4; ++ni) {
      int col = n0 + wn * 64 + ni * 16 + lg * 4;
      f32x4 v = acc[mi][ni] + b4[ni];
      size_t idx = (size_t)row * N + col;
      if (EPI == 0) {
        *(f32x4*)&outf[idx] = v;
      } else if (EPI == 1) {
        *(uint2*)&outb[idx] = pack_bf4(v);
      } else if (EPI == 2) {
        f32x4 g;
        #pragma unroll
        for (int e = 0; e < 4; ++e) g[e] = gelu1(v[e]);
        *(uint2*)&outb[idx] = pack_bf4(g);
      } else if (EPI == 3) {
        f32x4 g4 = *(const f32x4*)&gate[(size_t)bb * gstride + col];
        f32x4 xr = unpack_bf4(*(uint2*)&xres[idx]);
        xr += v * g4;
        *(uint2*)&xres[idx] = pack_bf4(xr);
      } else {
        f32x4* pp = (f32x4*)&outf[idx];
        __builtin_nontemporal_store(v, pp);
      }
    }
  }
}

// ---------------------------------------------------------------------------
// 128x128 BK=32 2-phase GEMM — kept for tiny grids (hnm). 2D grid.
// ---------------------------------------------------------------------------
template<int EPI>
__global__ __launch_bounds__(256)
void gemm_kernel(const u16* __restrict__ A, const u16* __restrict__ Bt,
                 const float* __restrict__ bias,
                 u16* __restrict__ outb, float* __restrict__ outf,
                 u16* __restrict__ xres, const float* __restrict__ gate, int gstride,
                 int M, int N, int K)
{
  __shared__ u16 ldsA[2][128 * 32];
  __shared__ u16 ldsB[2][128 * 32];
  const int tid = threadIdx.x;
  const int m0 = blockIdx.y << 7;
  const int n0 = blockIdx.x << 7;

  const int wid = tid >> 6, lane = tid & 63;
  const int wm = wid >> 1, wn = wid & 1;
  const int lr = lane & 15, lg = lane >> 4;

  f32x4 acc[4][4];
  #pragma unroll
  for (int i = 0; i < 4; ++i)
    #pragma unroll
    for (int j = 0; j < 4; ++j)
      acc[i][j] = (f32x4){0.f, 0.f, 0.f, 0.f};

  const int KT = K >> 5;
  int cur = 0;

  #define STAGE(buf, kt) do { \
    int k0_ = (kt) << 5; \
    _Pragma("unroll") \
    for (int iss = 0; iss < 2; ++iss) { \
      int f_ = iss * 256 + tid; \
      int row_ = f_ >> 2, gl_ = f_ & 3; \
      int g_ = gl_ ^ (row_ & 3); \
      GLDS(A + (size_t)(m0 + row_) * K + k0_ + g_ * 8, &ldsA[buf][f_ * 8]); \
      GLDS(Bt + (size_t)(n0 + row_) * K + k0_ + g_ * 8, &ldsB[buf][f_ * 8]); \
    } \
  } while (0)

  STAGE(0, 0);
  __syncthreads();
  for (int kt = 0; kt < KT; ++kt) {
    if (kt + 1 < KT) STAGE(cur ^ 1, kt + 1);
    bf16x8 af[4], bfr[4];
    #pragma unroll
    for (int i = 0; i < 4; ++i) {
      int ra = wm * 64 + i * 16 + lr;
      af[i] = *(const bf16x8*)&ldsA[cur][(ra * 4 + (lg ^ (ra & 3))) * 8];
      int rb = wn * 64 + i * 16 + lr;
      bfr[i] = *(const bf16x8*)&ldsB[cur][(rb * 4 + (lg ^ (rb & 3))) * 8];
    }
    #pragma unroll
    for (int mi = 0; mi < 4; ++mi)
      #pragma unroll
      for (int ni = 0; ni < 4; ++ni)
        acc[mi][ni] = __builtin_amdgcn_mfma_f32_16x16x32_bf16(bfr[ni], af[mi], acc[mi][ni], 0, 0, 0);
    __syncthreads();
    cur ^= 1;
  }
  #undef STAGE

  f32x4 b4[4];
  #pragma unroll
  for (int ni = 0; ni < 4; ++ni)
    b4[ni] = *(const f32x4*)&bias[n0 + wn * 64 + ni * 16 + lg * 4];

  #pragma unroll
  for (int mi = 0; mi < 4; ++mi) {
    int row = m0 + wm * 64 + mi * 16 + lr;
    int bb = row / 100;
    #pragma unroll
    for (int ni = 0; ni < 4; ++ni) {
      int col = n0 + wn * 64 + ni * 16 + lg * 4;
      f32x4 v = acc[mi][ni] + b4[ni];
      size_t idx = (size_t)row * N + col;
      if (EPI == 0) {
        *(f32x4*)&outf[idx] = v;
      } else if (EPI == 1) {
        *(uint2*)&outb[idx] = pack_bf4(v);
      } else if (EPI == 2) {
        f32x4 g;
        #pragma unroll
        for (int e = 0; e < 4; ++e) g[e] = gelu1(v[e]);
        *(uint2*)&outb[idx] = pack_bf4(g);
      } else {
        f32x4 g4 = *(const f32x4*)&gate[(size_t)bb * gstride + col];
        f32x4 xr = unpack_bf4(*(uint2*)&xres[idx]);
        xr += v * g4;
        *(uint2*)&xres[idx] = pack_bf4(xr);
      }
    }
  }
}

// ---------------------------------------------------------------------------
// Attention v2: 448 threads = 7 waves, one 16-row Q-strip per wave.
// Grid: blockIdx = h*128 + b. Dynamic LDS 72 KiB (2 blocks/CU).
// ---------------------------------------------------------------------------
__global__ __launch_bounds__(448)
void attn_kernel(const u16* __restrict__ qkv, u16* __restrict__ o)
{
  extern __shared__ u16 sm[];
  u16* Qs = sm;
  u16* Ks = Qs + 896 * 8;
  u16* Vt = Ks + 896 * 8;
  u16* Pl = Vt + 1024 * 8;
  const int tid = threadIdx.x;
  const int b = blockIdx.x & 127;
  const int h = blockIdx.x >> 7;
  const int wid = tid >> 6, lane = tid & 63;
  const int lr = lane & 15, lg = lane >> 4;
  const size_t qbase = (size_t)b * 100 * 2304 + h * 64;

  {
    u32* pw = (u32*)(Pl + wid * 256 * 8);
    #pragma unroll
    for (int i = 0; i < 16; ++i) pw[i * 64 + lane] = 0u;
  }

  #pragma unroll
  for (int it = 0; it < 2; ++it) {
    int idx = it * 448 + tid;
    int row = idx >> 3, gl = idx & 7;
    int g = gl ^ (row & 7);
    int sr = row < 100 ? row : 99;
    const u16* gq = qkv + qbase + (size_t)sr * 2304 + g * 8;
    GLDS(gq, &Qs[idx * 8]);
    GLDS(gq + 768, &Ks[idx * 8]);
  }

  #pragma unroll
  for (int it = 0; it < 2; ++it) {
    int idx = it * 448 + tid;
    if (idx < 896) {
      int k = idx >> 3, gd = idx & 7;
      int sk = k < 100 ? k : 99;
      const u16* gv = qkv + qbase + (size_t)sk * 2304 + 1536 + gd * 8;
      u16 vv[8];
      *(uint4*)vv = *(const uint4*)gv;
      #pragma unroll
      for (int e = 0; e < 8; ++e) {
        int d = gd * 8 + e;
        Vt[(d * 16 + ((k >> 3) ^ (d & 15))) * 8 + (k & 7)] = vv[e];
      }
    }
  }
  __syncthreads();

  const int s = wid;
  u16* Pw = Pl + wid * 256 * 8;

  f32x4 sa[7];
  #pragma unroll
  for (int nt = 0; nt < 7; ++nt) sa[nt] = (f32x4){0.f, 0.f, 0.f, 0.f};
  #pragma unroll
  for (int kk = 0; kk < 2; ++kk) {
    int qrow = s * 16 + lr;
    int qg = kk * 4 + lg;
    bf16x8 qa = *(const bf16x8*)&Qs[(qrow * 8 + (qg ^ (qrow & 7))) * 8];
    #pragma unroll
    for (int nt = 0; nt < 7; ++nt) {
      int krow = nt * 16 + lr;
      bf16x8 kb = *(const bf16x8*)&Ks[(krow * 8 + (qg ^ (krow & 7))) * 8];
      sa[nt] = __builtin_amdgcn_mfma_f32_16x16x32_bf16(qa, kb, sa[nt], 0, 0, 0);
    }
  }
  float pr[7][4];
  #pragma unroll
  for (int r = 0; r < 4; ++r) {
    int qq = s * 16 + lg * 4 + r;
    int kmax = qq < 10 ? 10 : qq < 30 ? 30 : qq < 60 ? 60 : 100;
    float m = -1e30f;
    #pragma unroll
    for (int nt = 0; nt < 7; ++nt) {
      int col = nt * 16 + lr;
      float sv = (col < kmax) ? sa[nt][r] * 0.125f : -1e30f;
      pr[nt][r] = sv;
      m = fmaxf(m, sv);
    }
    m = fmaxf(m, __shfl_xor(m, 1));
    m = fmaxf(m, __shfl_xor(m, 2));
    m = fmaxf(m, __shfl_xor(m, 4));
    m = fmaxf(m, __shfl_xor(m, 8));
    float sum = 0.f;
    #pragma unroll
    for (int nt = 0; nt < 7; ++nt) {
      float e = (pr[nt][r] > -1e29f) ? __expf(pr[nt][r] - m) : 0.f;
      pr[nt][r] = e;
      sum += e;
    }
    sum += __shfl_xor(sum, 1);
    sum += __shfl_xor(sum, 2);
    sum += __shfl_xor(sum, 4);
    sum += __shfl_xor(sum, 8);
    float inv = 1.f / sum;
    #pragma unroll
    for (int nt = 0; nt < 7; ++nt) pr[nt][r] *= inv;
  }
  #pragma unroll
  for (int nt = 0; nt < 7; ++nt) {
    int cg = nt * 2 + (lr >> 3);
    int e = lane & 7;
    #pragma unroll
    for (int r = 0; r < 4; ++r) {
      int row = lg * 4 + r;
      Pw[(row * 16 + (cg ^ row)) * 8 + e] = f2bf(pr[nt][r]);
    }
  }
  asm volatile("s_waitcnt lgkmcnt(0)" ::: "memory");
  f32x4 oa[4];
  #pragma unroll
  for (int i = 0; i < 4; ++i) oa[i] = (f32x4){0.f, 0.f, 0.f, 0.f};
  #pragma unroll
  for (int kk = 0; kk < 4; ++kk) {
    int prow = lr;
    int pg = kk * 4 + lg;
    bf16x8 pa = *(const bf16x8*)&Pw[(prow * 16 + (pg ^ prow)) * 8];
    #pragma unroll
    for (int nt = 0; nt < 4; ++nt) {
      int vrow = nt * 16 + lr;
      bf16x8 vb = *(const bf16x8*)&Vt[(vrow * 16 + (pg ^ (vrow & 15))) * 8];
      oa[nt] = __builtin_amdgcn_mfma_f32_16x16x32_bf16(vb, pa, oa[nt], 0, 0, 0);
    }
  }
  int qq = s * 16 + lr;
  if (qq < 100) {
    #pragma unroll
    for (int nt = 0; nt < 4; ++nt) {
      int d = nt * 16 + lg * 4;
      *(uint2*)&o[(size_t)(b * 100 + qq) * 768 + h * 64 + d] = pack_bf4(oa[nt]);
    }
  }
}

// ---------------------------------------------------------------------------
// 64x64 vectorized transpose+cast: fp32 (K,N) -> bf16 (N,K).
// ---------------------------------------------------------------------------
__global__ __launch_bounds__(256)
void transpose_cast64(const float* __restrict__ in, u16* __restrict__ out, int K, int N)
{
  __shared__ float tile[64][65];
  size_t zo = (size_t)blockIdx.z * K * N;
  const float* ip = in + zo;
  u16* op = out + zo;
  int n0 = blockIdx.x * 64, k0 = blockIdx.y * 64;
  int t = threadIdx.x;
  int lrow = t >> 4;
  int lcol = (t & 15) * 4;
  #pragma unroll
  for (int i = 0; i < 4; ++i) {
    int r = lrow + i * 16;
    f32x4 v = *(const f32x4*)&ip[(size_t)(k0 + r) * N + n0 + lcol];
    tile[r][lcol] = v[0]; tile[r][lcol + 1] = v[1];
    tile[r][lcol + 2] = v[2]; tile[r][lcol + 3] = v[3];
  }
  __syncthreads();
  #pragma unroll
  for (int j = 0; j < 4; ++j) {
    int nr = lrow + j * 16;
    f32x4 v;
    #pragma unroll
    for (int e = 0; e < 4; ++e) v[e] = tile[lcol + e][nr];
    *(uint2*)&op[(size_t)(n0 + nr) * K + k0 + lcol] = pack_bf4(v);
  }
}

__global__ __launch_bounds__(256)
void cond_kernel(const float* __restrict__ nobs, const float* __restrict__ obs_w,
                 const float* __restrict__ obs_b, float* __restrict__ cond,
                 u16* __restrict__ cond_s)
{
  int idx = blockIdx.x * 256 + threadIdx.x;
  int b = idx / 768, c = idx - b * 768;
  float acc = obs_b[c];
  #pragma unroll
  for (int i = 0; i < 23; ++i)
    acc += nobs[b * 23 + i] * obs_w[i * 768 + c];
  cond[idx] = acc;
  float sg = acc / (1.f + __expf(-acc));
  cond_s[idx] = f2bf(sg);
}

// ---------------------------------------------------------------------------
// Fused embedding: x[b][l] = (l<10 ? cond+pos_start : xv@word_w + word_b)
//                            + lvl_emb[LVL[l]] + pos_1LC[l],  bf16 out.
// word_w (32x768 fp32) staged once per block into 48KB LDS as bf16.
// 256 blocks x 50 rows; each thread covers cols {t, t+256, t+512}.
// Replaces cast_bf16 + word GEMM + build_x (removes 70MB fp32 round-trip).
// ---------------------------------------------------------------------------
__global__ __launch_bounds__(256)
void embed_kernel(const float* __restrict__ xv, const float* __restrict__ word_w,
                  const float* __restrict__ word_b,
                  const float* __restrict__ cond, const float* __restrict__ pos_start,
                  const float* __restrict__ lvl_emb, const float* __restrict__ pos_1LC,
                  u16* __restrict__ x)
{
  __shared__ u16 Wl[32 * 768];
  const int tid = threadIdx.x;
  #pragma unroll
  for (int i = 0; i < 96; ++i) {
    int idx = i * 256 + tid;
    Wl[idx] = f2bf(word_w[idx]);
  }
  __syncthreads();

  for (int rr = 0; rr < 50; ++rr) {
    int row = blockIdx.x * 50 + rr;
    int b = row / 100, l = row - b * 100;
    int lvl = l < 10 ? 0 : l < 30 ? 1 : l < 60 ? 2 : 3;
    float xk[32];
    if (l >= 10) {
      const float* xr = xv + (size_t)(b * 90 + (l - 10)) * 32;
      #pragma unroll
      for (int q = 0; q < 8; ++q) {
        f32x4 v4 = *(const f32x4*)&xr[q * 4];
        xk[q * 4] = v4[0]; xk[q * 4 + 1] = v4[1];
        xk[q * 4 + 2] = v4[2]; xk[q * 4 + 3] = v4[3];
      }
    }
    #pragma unroll
    for (int cc = 0; cc < 3; ++cc) {
      int c = cc * 256 + tid;
      float v;
      if (l < 10) {
        v = cond[b * 768 + c] + pos_start[l * 768 + c];
      } else {
        v = word_b[c];
        #pragma unroll
        for (int k = 0; k < 32; ++k)
          v += xk[k] * bf2f(Wl[k * 768 + c]);
      }
      v += lvl_emb[lvl * 768 + c] + pos_1LC[l * 768 + c];
      x[(size_t)row * 768 + c] = f2bf(v);
    }
  }
}

// ---------------------------------------------------------------------------
// LN + modulation: one WAVE per row (4 rows/block). BF16 x input.
// ---------------------------------------------------------------------------
__global__ __launch_bounds__(256)
void ln_mod_kernel(const u16* __restrict__ x, const float* __restrict__ scale_b,
                   const float* __restrict__ shift_b, int stride, u16* __restrict__ h)
{
  const int tid = threadIdx.x;
  const int wid = tid >> 6, lane = tid & 63;
  const int row = blockIdx.x * 4 + wid;
  const u16* xr = x + (size_t)row * 768;

  f32x4 v[3];
  #pragma unroll
  for (int c = 0; c < 3; ++c)
    v[c] = unpack_bf4(*(const uint2*)&xr[c * 256 + lane * 4]);

  float s = 0.f, qv = 0.f;
  #pragma unroll
  for (int c = 0; c < 3; ++c)
    #pragma unroll
    for (int e = 0; e < 4; ++e) { s += v[c][e]; qv += v[c][e] * v[c][e]; }
  #pragma unroll
  for (int o = 32; o > 0; o >>= 1) {
    s += __shfl_xor(s, o);
    qv += __shfl_xor(qv, o);
  }
  float mean = s * (1.f / 768.f);
  float var = qv * (1.f / 768.f) - mean * mean;
  float rstd = rsqrtf(var + 1e-6f);

  const int bb = row / 100;
  const float* sc = scale_b + (size_t)bb * stride;
  const float* sh = shift_b + (size_t)bb * stride;
  u16* hr = h + (size_t)row * 768;
  #pragma unroll
  for (int c = 0; c < 3; ++c) {
    f32x4 s4 = *(const f32x4*)&sc[c * 256 + lane * 4];
    f32x4 h4 = *(const f32x4*)&sh[c * 256 + lane * 4];
    f32x4 o4;
    #pragma unroll
    for (int e = 0; e < 4; ++e)
      o4[e] = (v[c][e] - mean) * rstd * (1.f + s4[e]) + h4[e];
    *(uint2*)&hr[c * 256 + lane * 4] = pack_bf4(o4);
  }
}

// ---------------------------------------------------------------------------
extern "C" void kernel_launch(void* const* d_in, const int* in_sizes, int n_in,
                              void* d_out, int out_size, void* d_ws, size_t ws_size,
                              hipStream_t stream)
{
  (void)in_sizes; (void)n_in; (void)out_size;
  const float* nobs      = (const float*)d_in[0];
  const float* xv        = (const float*)d_in[1];
  const float* obs_w     = (const float*)d_in[2];
  const float* obs_b     = (const float*)d_in[3];
  const float* word_w    = (const float*)d_in[4];
  const float* word_b    = (const float*)d_in[5];
  const float* pos_start = (const float*)d_in[6];
  const float* pos_1LC   = (const float*)d_in[7];
  const float* lvl_emb   = (const float*)d_in[8];
  const float* ada_w     = (const float*)d_in[9];
  const float* ada_b     = (const float*)d_in[10];
  const float* qkv_w     = (const float*)d_in[11];
  const float* qkv_b     = (const float*)d_in[12];
  const float* proj_w    = (const float*)d_in[13];
  const float* proj_b    = (const float*)d_in[14];
  const float* fc1_w     = (const float*)d_in[15];
  const float* fc1_b     = (const float*)d_in[16];
  const float* fc2_w     = (const float*)d_in[17];
  const float* fc2_b     = (const float*)d_in[18];
  const float* hnm_w     = (const float*)d_in[19];
  const float* hnm_b     = (const float*)d_in[20];
  const float* head_w    = (const float*)d_in[21];
  const float* head_b    = (const float*)d_in[22];
  float* out = (float*)d_out;

  const size_t NEED_BIG = 358000000;
  const bool bigAda = ws_size >= NEED_BIG;
  const int adaStride = bigAda ? 36864 : 4608;

  char* p = (char*)d_ws;
  auto take = [&](size_t bytes) { char* r = p; p += (bytes + 255) & ~(size_t)255; return r; };
  u16* Wada    = (u16*)take((size_t)8 * 4608 * 768 * 2);
  u16* Wqkv    = (u16*)take((size_t)8 * 2304 * 768 * 2);
  u16* Wproj   = (u16*)take((size_t)8 * 768 * 768 * 2);
  u16* Wfc1    = (u16*)take((size_t)8 * 3072 * 768 * 2);
  u16* Wfc2    = (u16*)take((size_t)8 * 768 * 3072 * 2);
  u16* Whnm    = (u16*)take((size_t)1536 * 768 * 2);
  u16* Whead   = (u16*)take((size_t)4096 * 768 * 2);
  float* condf = (float*)take((size_t)128 * 768 * 4);
  u16* conds   = (u16*)take((size_t)128 * 768 * 2);
  u16* xbuf    = (u16*)take((size_t)12800 * 768 * 2);   // BF16 residual stream
  u16* hbuf    = (u16*)take((size_t)12800 * 768 * 2);
  float* adab  = (float*)take((size_t)128 * (size_t)adaStride * 4);
  u16* obuf    = (u16*)take((size_t)12800 * 768 * 2);
  float* hdbuf = (float*)take((size_t)128 * 1536 * 4);
  char* big    = take((size_t)12800 * 3072 * 2);
  u16* qkvb  = (u16*)big;
  u16* fc1b  = (u16*)big;

  (void)hipFuncSetAttribute(reinterpret_cast<const void*>(&attn_kernel),
                            hipFuncAttributeMaxDynamicSharedMemorySize, 73728);

  // ---- weight transposes (fp32 (K,N) -> bf16 (N,K)) ----
  transpose_cast64<<<dim3(72, 12, 8), 256, 0, stream>>>(ada_w,  Wada,  768, 4608);
  transpose_cast64<<<dim3(36, 12, 8), 256, 0, stream>>>(qkv_w,  Wqkv,  768, 2304);
  transpose_cast64<<<dim3(12, 12, 8), 256, 0, stream>>>(proj_w, Wproj, 768, 768);
  transpose_cast64<<<dim3(48, 12, 8), 256, 0, stream>>>(fc1_w,  Wfc1,  768, 3072);
  transpose_cast64<<<dim3(12, 48, 8), 256, 0, stream>>>(fc2_w,  Wfc2,  3072, 768);
  transpose_cast64<<<dim3(24, 12, 1), 256, 0, stream>>>(hnm_w,  Whnm,  768, 1536);
  transpose_cast64<<<dim3(64, 12, 1), 256, 0, stream>>>(head_w, Whead, 768, 4096);

  // ---- prologue (fused embedding) ----
  cond_kernel<<<384, 256, 0, stream>>>(nobs, obs_w, obs_b, condf, conds);
  embed_kernel<<<256, 256, 0, stream>>>(xv, word_w, word_b, condf, pos_start,
                                        lvl_emb, pos_1LC, xbuf);

  // merged adaLN GEMM for all 8 layers (M=128, N=36864, K=768)
  if (bigAda)
    gemm64_kernel<0><<<dim3(288, 1), 256, 0, stream>>>(conds, Wada, ada_b,
        nullptr, adab, nullptr, nullptr, 0, 128, 36864, 768);

  // ---- transformer layers ----
  for (int i = 0; i < 8; ++i) {
    if (!bigAda)
      gemm64_kernel<0><<<dim3(36, 1), 256, 0, stream>>>(conds, Wada + (size_t)i * 4608 * 768,
          ada_b + (size_t)i * 4608, nullptr, adab, nullptr, nullptr, 0, 128, 4608, 768);
    float* adaL = bigAda ? adab + (size_t)i * 4608 : adab;
    // slots: 0=g1 1=g2 2=s1 3=s2 4=sh1 5=sh2
    ln_mod_kernel<<<3200, 256, 0, stream>>>(xbuf, adaL + 2 * 768, adaL + 4 * 768, adaStride, hbuf);
    gemm64_kernel<1><<<dim3(18, 100), 256, 0, stream>>>(hbuf, Wqkv + (size_t)i * 2304 * 768,
        qkv_b + (size_t)i * 2304, qkvb, nullptr, nullptr, nullptr, 0, 12800, 2304, 768);
    attn_kernel<<<1536, 448, 73728, stream>>>(qkvb, obuf);
    gemm64_kernel<3><<<dim3(6, 100), 256, 0, stream>>>(obuf, Wproj + (size_t)i * 768 * 768,
        proj_b + (size_t)i * 768, nullptr, nullptr, xbuf, adaL + 0 * 768, adaStride, 12800, 768, 768);
    ln_mod_kernel<<<3200, 256, 0, stream>>>(xbuf, adaL + 3 * 768, adaL + 5 * 768, adaStride, hbuf);
    gemm64_kernel<2><<<dim3(24, 100), 256, 0, stream>>>(hbuf, Wfc1 + (size_t)i * 3072 * 768,
        fc1_b + (size_t)i * 3072, fc1b, nullptr, nullptr, nullptr, 0, 12800, 3072, 768);
    gemm64_kernel<3><<<dim3(6, 100), 256, 0, stream>>>(fc1b, Wfc2 + (size_t)i * 768 * 3072,
        fc2_b + (size_t)i * 768, nullptr, nullptr, xbuf, adaL + 1 * 768, adaStride, 12800, 768, 3072);
  }

  // ---- head ----
  gemm_kernel<0><<<dim3(12, 1), 256, 0, stream>>>(conds, Whnm, hnm_b,
      nullptr, hdbuf, nullptr, nullptr, 0, 128, 1536, 768);
  ln_mod_kernel<<<3200, 256, 0, stream>>>(xbuf, hdbuf, hdbuf + 768, 1536, hbuf);
  gemm64_kernel<4><<<dim3(32, 100), 256, 0, stream>>>(hbuf, Whead, head_b,
      nullptr, out, nullptr, nullptr, 0, 12800, 4096, 768);
}

// Round 14
// 3074.648 us; speedup vs baseline: 1.0285x; 1.0285x over previous
//
#include <hip/hip_runtime.h>
#include <hip/hip_bf16.h>

typedef unsigned short u16;
typedef unsigned int u32;
typedef __attribute__((ext_vector_type(8))) short bf16x8;
typedef __attribute__((ext_vector_type(4))) float f32x4;

#define GLDS(gptr, lptr) __builtin_amdgcn_global_load_lds( \
    (const __attribute__((address_space(1))) u32*)(gptr), \
    (__attribute__((address_space(3))) u32*)(lptr), 16, 0, 0)

__device__ __forceinline__ float bf2f(u16 x) {
  union { float f; u32 u; } c; c.u = ((u32)x) << 16; return c.f;
}
__device__ __forceinline__ u16 f2bf(float f) {
  union { float f; u32 u; } c; c.f = f;
  u32 u = c.u;
  return (u16)((u + 0x7FFFu + ((u >> 16) & 1u)) >> 16);
}
__device__ __forceinline__ uint2 pack_bf4(f32x4 v) {
  uint2 pk;
  pk.x = ((u32)f2bf(v[1]) << 16) | (u32)f2bf(v[0]);
  pk.y = ((u32)f2bf(v[3]) << 16) | (u32)f2bf(v[2]);
  return pk;
}
__device__ __forceinline__ f32x4 unpack_bf4(uint2 pk) {
  f32x4 v;
  v[0] = bf2f((u16)(pk.x & 0xFFFF));
  v[1] = bf2f((u16)(pk.x >> 16));
  v[2] = bf2f((u16)(pk.y & 0xFFFF));
  v[3] = bf2f((u16)(pk.y >> 16));
  return v;
}
__device__ __forceinline__ float gelu1(float v) {
  float t = 0.7978845608028654f * (v + 0.044715f * v * v * v);
  t = fminf(fmaxf(t, -15.f), 15.f);
  float e = __expf(2.f * t);
  return 0.5f * v * (1.f + (e - 1.f) / (e + 1.f));
}

// ---------------------------------------------------------------------------
// 128x128, BK=64 2-phase GEMM — 256 threads / 4 waves (2x2), per-wave 64x64.
// (R10/R12 config — best measured.)
// EPI: 0 = fp32 store, 1 = bf16 store, 2 = gelu->bf16,
//      3 = gated residual into BF16 xres, 4 = fp32 non-temporal store
// ---------------------------------------------------------------------------
template<int EPI>
__global__ __launch_bounds__(256)
void gemm64_kernel(const u16* __restrict__ A, const u16* __restrict__ Bt,
                   const float* __restrict__ bias,
                   u16* __restrict__ outb, float* __restrict__ outf,
                   u16* __restrict__ xres, const float* __restrict__ gate, int gstride,
                   int M, int N, int K)
{
  __shared__ u16 ldsA[2][128 * 64];
  __shared__ u16 ldsB[2][128 * 64];
  const int tid = threadIdx.x;
  const int m0 = blockIdx.y << 7;
  const int n0 = blockIdx.x << 7;

  const int wid = tid >> 6, lane = tid & 63;
  const int wm = wid >> 1, wn = wid & 1;
  const int lr = lane & 15, lg = lane >> 4;

  f32x4 acc[4][4];
  #pragma unroll
  for (int i = 0; i < 4; ++i)
    #pragma unroll
    for (int j = 0; j < 4; ++j)
      acc[i][j] = (f32x4){0.f, 0.f, 0.f, 0.f};

  const int KT = K >> 6;
  int cur = 0;

  #define STAGE64(buf, kt) do { \
    int k0_ = (kt) << 6; \
    _Pragma("unroll") \
    for (int iss = 0; iss < 4; ++iss) { \
      int f_ = iss * 256 + tid; \
      int row_ = f_ >> 3, gl_ = f_ & 7; \
      int g_ = gl_ ^ (row_ & 7); \
      GLDS(A + (size_t)(m0 + row_) * K + k0_ + g_ * 8, &ldsA[buf][f_ * 8]); \
      GLDS(Bt + (size_t)(n0 + row_) * K + k0_ + g_ * 8, &ldsB[buf][f_ * 8]); \
    } \
  } while (0)

  STAGE64(0, 0);
  __syncthreads();
  for (int kt = 0; kt < KT; ++kt) {
    if (kt + 1 < KT) STAGE64(cur ^ 1, kt + 1);
    #pragma unroll
    for (int kk = 0; kk < 2; ++kk) {
      bf16x8 af[4], bv[4];
      #pragma unroll
      for (int i = 0; i < 4; ++i) {
        int ra = wm * 64 + i * 16 + lr;
        int da = kk * 4 + lg;
        af[i] = *(const bf16x8*)&ldsA[cur][(ra * 8 + (da ^ (ra & 7))) * 8];
        int rb = wn * 64 + i * 16 + lr;
        bv[i] = *(const bf16x8*)&ldsB[cur][(rb * 8 + (da ^ (rb & 7))) * 8];
      }
      #pragma unroll
      for (int mi = 0; mi < 4; ++mi)
        #pragma unroll
        for (int ni = 0; ni < 4; ++ni)
          acc[mi][ni] = __builtin_amdgcn_mfma_f32_16x16x32_bf16(bv[ni], af[mi], acc[mi][ni], 0, 0, 0);
    }
    __syncthreads();
    cur ^= 1;
  }
  #undef STAGE64

  f32x4 b4[4];
  #pragma unroll
  for (int ni = 0; ni < 4; ++ni)
    b4[ni] = *(const f32x4*)&bias[n0 + wn * 64 + ni * 16 + lg * 4];

  #pragma unroll
  for (int mi = 0; mi < 4; ++mi) {
    int row = m0 + wm * 64 + mi * 16 + lr;
    int bb = row / 100;
    #pragma unroll
    for (int ni = 0; ni < 4; ++ni) {
      int col = n0 + wn * 64 + ni * 16 + lg * 4;
      f32x4 v = acc[mi][ni] + b4[ni];
      size_t idx = (size_t)row * N + col;
      if (EPI == 0) {
        *(f32x4*)&outf[idx] = v;
      } else if (EPI == 1) {
        *(uint2*)&outb[idx] = pack_bf4(v);
      } else if (EPI == 2) {
        f32x4 g;
        #pragma unroll
        for (int e = 0; e < 4; ++e) g[e] = gelu1(v[e]);
        *(uint2*)&outb[idx] = pack_bf4(g);
      } else if (EPI == 3) {
        f32x4 g4 = *(const f32x4*)&gate[(size_t)bb * gstride + col];
        f32x4 xr = unpack_bf4(*(uint2*)&xres[idx]);
        xr += v * g4;
        *(uint2*)&xres[idx] = pack_bf4(xr);
      } else {
        f32x4* pp = (f32x4*)&outf[idx];
        __builtin_nontemporal_store(v, pp);
      }
    }
  }
}

// ---------------------------------------------------------------------------
// 128x128 BK=32 2-phase GEMM — for K=32 (word) and tiny grids (hnm). 2D grid.
// ---------------------------------------------------------------------------
template<int EPI>
__global__ __launch_bounds__(256)
void gemm_kernel(const u16* __restrict__ A, const u16* __restrict__ Bt,
                 const float* __restrict__ bias,
                 u16* __restrict__ outb, float* __restrict__ outf,
                 u16* __restrict__ xres, const float* __restrict__ gate, int gstride,
                 int M, int N, int K)
{
  __shared__ u16 ldsA[2][128 * 32];
  __shared__ u16 ldsB[2][128 * 32];
  const int tid = threadIdx.x;
  const int m0 = blockIdx.y << 7;
  const int n0 = blockIdx.x << 7;

  const int wid = tid >> 6, lane = tid & 63;
  const int wm = wid >> 1, wn = wid & 1;
  const int lr = lane & 15, lg = lane >> 4;

  f32x4 acc[4][4];
  #pragma unroll
  for (int i = 0; i < 4; ++i)
    #pragma unroll
    for (int j = 0; j < 4; ++j)
      acc[i][j] = (f32x4){0.f, 0.f, 0.f, 0.f};

  const int KT = K >> 5;
  int cur = 0;

  #define STAGE(buf, kt) do { \
    int k0_ = (kt) << 5; \
    _Pragma("unroll") \
    for (int iss = 0; iss < 2; ++iss) { \
      int f_ = iss * 256 + tid; \
      int row_ = f_ >> 2, gl_ = f_ & 3; \
      int g_ = gl_ ^ (row_ & 3); \
      GLDS(A + (size_t)(m0 + row_) * K + k0_ + g_ * 8, &ldsA[buf][f_ * 8]); \
      GLDS(Bt + (size_t)(n0 + row_) * K + k0_ + g_ * 8, &ldsB[buf][f_ * 8]); \
    } \
  } while (0)

  STAGE(0, 0);
  __syncthreads();
  for (int kt = 0; kt < KT; ++kt) {
    if (kt + 1 < KT) STAGE(cur ^ 1, kt + 1);
    bf16x8 af[4], bfr[4];
    #pragma unroll
    for (int i = 0; i < 4; ++i) {
      int ra = wm * 64 + i * 16 + lr;
      af[i] = *(const bf16x8*)&ldsA[cur][(ra * 4 + (lg ^ (ra & 3))) * 8];
      int rb = wn * 64 + i * 16 + lr;
      bfr[i] = *(const bf16x8*)&ldsB[cur][(rb * 4 + (lg ^ (rb & 3))) * 8];
    }
    #pragma unroll
    for (int mi = 0; mi < 4; ++mi)
      #pragma unroll
      for (int ni = 0; ni < 4; ++ni)
        acc[mi][ni] = __builtin_amdgcn_mfma_f32_16x16x32_bf16(bfr[ni], af[mi], acc[mi][ni], 0, 0, 0);
    __syncthreads();
    cur ^= 1;
  }
  #undef STAGE

  f32x4 b4[4];
  #pragma unroll
  for (int ni = 0; ni < 4; ++ni)
    b4[ni] = *(const f32x4*)&bias[n0 + wn * 64 + ni * 16 + lg * 4];

  #pragma unroll
  for (int mi = 0; mi < 4; ++mi) {
    int row = m0 + wm * 64 + mi * 16 + lr;
    int bb = row / 100;
    #pragma unroll
    for (int ni = 0; ni < 4; ++ni) {
      int col = n0 + wn * 64 + ni * 16 + lg * 4;
      f32x4 v = acc[mi][ni] + b4[ni];
      size_t idx = (size_t)row * N + col;
      if (EPI == 0) {
        *(f32x4*)&outf[idx] = v;
      } else if (EPI == 1) {
        *(uint2*)&outb[idx] = pack_bf4(v);
      } else if (EPI == 2) {
        f32x4 g;
        #pragma unroll
        for (int e = 0; e < 4; ++e) g[e] = gelu1(v[e]);
        *(uint2*)&outb[idx] = pack_bf4(g);
      } else {
        f32x4 g4 = *(const f32x4*)&gate[(size_t)bb * gstride + col];
        f32x4 xr = unpack_bf4(*(uint2*)&xres[idx]);
        xr += v * g4;
        *(uint2*)&xres[idx] = pack_bf4(xr);
      }
    }
  }
}

// ---------------------------------------------------------------------------
// Attention v2: 448 threads = 7 waves, one 16-row Q-strip per wave.
// Grid: blockIdx = h*128 + b. Dynamic LDS 72 KiB (2 blocks/CU).
// ---------------------------------------------------------------------------
__global__ __launch_bounds__(448)
void attn_kernel(const u16* __restrict__ qkv, u16* __restrict__ o)
{
  extern __shared__ u16 sm[];
  u16* Qs = sm;
  u16* Ks = Qs + 896 * 8;
  u16* Vt = Ks + 896 * 8;
  u16* Pl = Vt + 1024 * 8;
  const int tid = threadIdx.x;
  const int b = blockIdx.x & 127;
  const int h = blockIdx.x >> 7;
  const int wid = tid >> 6, lane = tid & 63;
  const int lr = lane & 15, lg = lane >> 4;
  const size_t qbase = (size_t)b * 100 * 2304 + h * 64;

  {
    u32* pw = (u32*)(Pl + wid * 256 * 8);
    #pragma unroll
    for (int i = 0; i < 16; ++i) pw[i * 64 + lane] = 0u;
  }

  #pragma unroll
  for (int it = 0; it < 2; ++it) {
    int idx = it * 448 + tid;
    int row = idx >> 3, gl = idx & 7;
    int g = gl ^ (row & 7);
    int sr = row < 100 ? row : 99;
    const u16* gq = qkv + qbase + (size_t)sr * 2304 + g * 8;
    GLDS(gq, &Qs[idx * 8]);
    GLDS(gq + 768, &Ks[idx * 8]);
  }

  #pragma unroll
  for (int it = 0; it < 2; ++it) {
    int idx = it * 448 + tid;
    if (idx < 896) {
      int k = idx >> 3, gd = idx & 7;
      int sk = k < 100 ? k : 99;
      const u16* gv = qkv + qbase + (size_t)sk * 2304 + 1536 + gd * 8;
      u16 vv[8];
      *(uint4*)vv = *(const uint4*)gv;
      #pragma unroll
      for (int e = 0; e < 8; ++e) {
        int d = gd * 8 + e;
        Vt[(d * 16 + ((k >> 3) ^ (d & 15))) * 8 + (k & 7)] = vv[e];
      }
    }
  }
  __syncthreads();

  const int s = wid;
  u16* Pw = Pl + wid * 256 * 8;

  f32x4 sa[7];
  #pragma unroll
  for (int nt = 0; nt < 7; ++nt) sa[nt] = (f32x4){0.f, 0.f, 0.f, 0.f};
  #pragma unroll
  for (int kk = 0; kk < 2; ++kk) {
    int qrow = s * 16 + lr;
    int qg = kk * 4 + lg;
    bf16x8 qa = *(const bf16x8*)&Qs[(qrow * 8 + (qg ^ (qrow & 7))) * 8];
    #pragma unroll
    for (int nt = 0; nt < 7; ++nt) {
      int krow = nt * 16 + lr;
      bf16x8 kb = *(const bf16x8*)&Ks[(krow * 8 + (qg ^ (krow & 7))) * 8];
      sa[nt] = __builtin_amdgcn_mfma_f32_16x16x32_bf16(qa, kb, sa[nt], 0, 0, 0);
    }
  }
  float pr[7][4];
  #pragma unroll
  for (int r = 0; r < 4; ++r) {
    int qq = s * 16 + lg * 4 + r;
    int kmax = qq < 10 ? 10 : qq < 30 ? 30 : qq < 60 ? 60 : 100;
    float m = -1e30f;
    #pragma unroll
    for (int nt = 0; nt < 7; ++nt) {
      int col = nt * 16 + lr;
      float sv = (col < kmax) ? sa[nt][r] * 0.125f : -1e30f;
      pr[nt][r] = sv;
      m = fmaxf(m, sv);
    }
    m = fmaxf(m, __shfl_xor(m, 1));
    m = fmaxf(m, __shfl_xor(m, 2));
    m = fmaxf(m, __shfl_xor(m, 4));
    m = fmaxf(m, __shfl_xor(m, 8));
    float sum = 0.f;
    #pragma unroll
    for (int nt = 0; nt < 7; ++nt) {
      float e = (pr[nt][r] > -1e29f) ? __expf(pr[nt][r] - m) : 0.f;
      pr[nt][r] = e;
      sum += e;
    }
    sum += __shfl_xor(sum, 1);
    sum += __shfl_xor(sum, 2);
    sum += __shfl_xor(sum, 4);
    sum += __shfl_xor(sum, 8);
    float inv = 1.f / sum;
    #pragma unroll
    for (int nt = 0; nt < 7; ++nt) pr[nt][r] *= inv;
  }
  #pragma unroll
  for (int nt = 0; nt < 7; ++nt) {
    int cg = nt * 2 + (lr >> 3);
    int e = lane & 7;
    #pragma unroll
    for (int r = 0; r < 4; ++r) {
      int row = lg * 4 + r;
      Pw[(row * 16 + (cg ^ row)) * 8 + e] = f2bf(pr[nt][r]);
    }
  }
  asm volatile("s_waitcnt lgkmcnt(0)" ::: "memory");
  f32x4 oa[4];
  #pragma unroll
  for (int i = 0; i < 4; ++i) oa[i] = (f32x4){0.f, 0.f, 0.f, 0.f};
  #pragma unroll
  for (int kk = 0; kk < 4; ++kk) {
    int prow = lr;
    int pg = kk * 4 + lg;
    bf16x8 pa = *(const bf16x8*)&Pw[(prow * 16 + (pg ^ prow)) * 8];
    #pragma unroll
    for (int nt = 0; nt < 4; ++nt) {
      int vrow = nt * 16 + lr;
      bf16x8 vb = *(const bf16x8*)&Vt[(vrow * 16 + (pg ^ (vrow & 15))) * 8];
      oa[nt] = __builtin_amdgcn_mfma_f32_16x16x32_bf16(vb, pa, oa[nt], 0, 0, 0);
    }
  }
  int qq = s * 16 + lr;
  if (qq < 100) {
    #pragma unroll
    for (int nt = 0; nt < 4; ++nt) {
      int d = nt * 16 + lg * 4;
      *(uint2*)&o[(size_t)(b * 100 + qq) * 768 + h * 64 + d] = pack_bf4(oa[nt]);
    }
  }
}

// ---------------------------------------------------------------------------
// 64x64 vectorized transpose+cast: fp32 (K,N) -> bf16 (N,K).
// ---------------------------------------------------------------------------
__global__ __launch_bounds__(256)
void transpose_cast64(const float* __restrict__ in, u16* __restrict__ out, int K, int N)
{
  __shared__ float tile[64][65];
  size_t zo = (size_t)blockIdx.z * K * N;
  const float* ip = in + zo;
  u16* op = out + zo;
  int n0 = blockIdx.x * 64, k0 = blockIdx.y * 64;
  int t = threadIdx.x;
  int lrow = t >> 4;
  int lcol = (t & 15) * 4;
  #pragma unroll
  for (int i = 0; i < 4; ++i) {
    int r = lrow + i * 16;
    f32x4 v = *(const f32x4*)&ip[(size_t)(k0 + r) * N + n0 + lcol];
    tile[r][lcol] = v[0]; tile[r][lcol + 1] = v[1];
    tile[r][lcol + 2] = v[2]; tile[r][lcol + 3] = v[3];
  }
  __syncthreads();
  #pragma unroll
  for (int j = 0; j < 4; ++j) {
    int nr = lrow + j * 16;
    f32x4 v;
    #pragma unroll
    for (int e = 0; e < 4; ++e) v[e] = tile[lcol + e][nr];
    *(uint2*)&op[(size_t)(n0 + nr) * K + k0 + lcol] = pack_bf4(v);
  }
}

// 32x32 transpose+cast (kept for word_w: K=32)
__global__ __launch_bounds__(256)
void transpose_cast(const float* __restrict__ in, u16* __restrict__ out, int K, int N)
{
  __shared__ float tile[32][33];
  size_t zo = (size_t)blockIdx.z * K * N;
  const float* ip = in + zo;
  u16* op = out + zo;
  int n0 = blockIdx.x * 32, k0 = blockIdx.y * 32;
  int tx = threadIdx.x & 31, ty = threadIdx.x >> 5;
  #pragma unroll
  for (int i = 0; i < 32; i += 8)
    tile[ty + i][tx] = ip[(size_t)(k0 + ty + i) * N + n0 + tx];
  __syncthreads();
  #pragma unroll
  for (int i = 0; i < 32; i += 8)
    op[(size_t)(n0 + ty + i) * K + k0 + tx] = f2bf(tile[tx][ty + i]);
}

__global__ __launch_bounds__(256)
void cond_kernel(const float* __restrict__ nobs, const float* __restrict__ obs_w,
                 const float* __restrict__ obs_b, float* __restrict__ cond,
                 u16* __restrict__ cond_s)
{
  int idx = blockIdx.x * 256 + threadIdx.x;
  int b = idx / 768, c = idx - b * 768;
  float acc = obs_b[c];
  #pragma unroll
  for (int i = 0; i < 23; ++i)
    acc += nobs[b * 23 + i] * obs_w[i * 768 + c];
  cond[idx] = acc;
  float sg = acc / (1.f + __expf(-acc));
  cond_s[idx] = f2bf(sg);
}

__global__ __launch_bounds__(256)
void cast_bf16_kernel(const float* __restrict__ in, u16* __restrict__ out, int n)
{
  int idx = blockIdx.x * 256 + threadIdx.x;
  if (idx < n) out[idx] = f2bf(in[idx]);
}

__global__ __launch_bounds__(256)
void build_x_kernel(const float* __restrict__ cond, const float* __restrict__ pos_start,
                    const float* __restrict__ xw, const float* __restrict__ lvl_emb,
                    const float* __restrict__ pos_1LC, u16* __restrict__ x)
{
  int idx4 = (blockIdx.x * 256 + threadIdx.x) * 4;
  int row = idx4 / 768, c = idx4 - row * 768;
  int b = row / 100, l = row - b * 100;
  int lvl = l < 10 ? 0 : l < 30 ? 1 : l < 60 ? 2 : 3;
  f32x4 v;
  if (l < 10) {
    v = *(const f32x4*)&cond[b * 768 + c];
    v += *(const f32x4*)&pos_start[l * 768 + c];
  } else {
    v = *(const f32x4*)&xw[(size_t)(b * 90 + (l - 10)) * 768 + c];
  }
  v += *(const f32x4*)&lvl_emb[lvl * 768 + c];
  v += *(const f32x4*)&pos_1LC[l * 768 + c];
  *(uint2*)&x[idx4] = pack_bf4(v);
}

// ---------------------------------------------------------------------------
// LN + modulation: one WAVE per row (4 rows/block). BF16 x input.
// ---------------------------------------------------------------------------
__global__ __launch_bounds__(256)
void ln_mod_kernel(const u16* __restrict__ x, const float* __restrict__ scale_b,
                   const float* __restrict__ shift_b, int stride, u16* __restrict__ h)
{
  const int tid = threadIdx.x;
  const int wid = tid >> 6, lane = tid & 63;
  const int row = blockIdx.x * 4 + wid;
  const u16* xr = x + (size_t)row * 768;

  f32x4 v[3];
  #pragma unroll
  for (int c = 0; c < 3; ++c)
    v[c] = unpack_bf4(*(const uint2*)&xr[c * 256 + lane * 4]);

  float s = 0.f, qv = 0.f;
  #pragma unroll
  for (int c = 0; c < 3; ++c)
    #pragma unroll
    for (int e = 0; e < 4; ++e) { s += v[c][e]; qv += v[c][e] * v[c][e]; }
  #pragma unroll
  for (int o = 32; o > 0; o >>= 1) {
    s += __shfl_xor(s, o);
    qv += __shfl_xor(qv, o);
  }
  float mean = s * (1.f / 768.f);
  float var = qv * (1.f / 768.f) - mean * mean;
  float rstd = rsqrtf(var + 1e-6f);

  const int bb = row / 100;
  const float* sc = scale_b + (size_t)bb * stride;
  const float* sh = shift_b + (size_t)bb * stride;
  u16* hr = h + (size_t)row * 768;
  #pragma unroll
  for (int c = 0; c < 3; ++c) {
    f32x4 s4 = *(const f32x4*)&sc[c * 256 + lane * 4];
    f32x4 h4 = *(const f32x4*)&sh[c * 256 + lane * 4];
    f32x4 o4;
    #pragma unroll
    for (int e = 0; e < 4; ++e)
      o4[e] = (v[c][e] - mean) * rstd * (1.f + s4[e]) + h4[e];
    *(uint2*)&hr[c * 256 + lane * 4] = pack_bf4(o4);
  }
}

// ---------------------------------------------------------------------------
extern "C" void kernel_launch(void* const* d_in, const int* in_sizes, int n_in,
                              void* d_out, int out_size, void* d_ws, size_t ws_size,
                              hipStream_t stream)
{
  (void)in_sizes; (void)n_in; (void)out_size;
  const float* nobs      = (const float*)d_in[0];
  const float* xv        = (const float*)d_in[1];
  const float* obs_w     = (const float*)d_in[2];
  const float* obs_b     = (const float*)d_in[3];
  const float* word_w    = (const float*)d_in[4];
  const float* word_b    = (const float*)d_in[5];
  const float* pos_start = (const float*)d_in[6];
  const float* pos_1LC   = (const float*)d_in[7];
  const float* lvl_emb   = (const float*)d_in[8];
  const float* ada_w     = (const float*)d_in[9];
  const float* ada_b     = (const float*)d_in[10];
  const float* qkv_w     = (const float*)d_in[11];
  const float* qkv_b     = (const float*)d_in[12];
  const float* proj_w    = (const float*)d_in[13];
  const float* proj_b    = (const float*)d_in[14];
  const float* fc1_w     = (const float*)d_in[15];
  const float* fc1_b     = (const float*)d_in[16];
  const float* fc2_w     = (const float*)d_in[17];
  const float* fc2_b     = (const float*)d_in[18];
  const float* hnm_w     = (const float*)d_in[19];
  const float* hnm_b     = (const float*)d_in[20];
  const float* head_w    = (const float*)d_in[21];
  const float* head_b    = (const float*)d_in[22];
  float* out = (float*)d_out;

  const size_t NEED_BIG = 358000000;
  const bool bigAda = ws_size >= NEED_BIG;
  const int adaStride = bigAda ? 36864 : 4608;

  char* p = (char*)d_ws;
  auto take = [&](size_t bytes) { char* r = p; p += (bytes + 255) & ~(size_t)255; return r; };
  u16* Wword   = (u16*)take((size_t)768 * 32 * 2);
  u16* Wada    = (u16*)take((size_t)8 * 4608 * 768 * 2);
  u16* Wqkv    = (u16*)take((size_t)8 * 2304 * 768 * 2);
  u16* Wproj   = (u16*)take((size_t)8 * 768 * 768 * 2);
  u16* Wfc1    = (u16*)take((size_t)8 * 3072 * 768 * 2);
  u16* Wfc2    = (u16*)take((size_t)8 * 768 * 3072 * 2);
  u16* Whnm    = (u16*)take((size_t)1536 * 768 * 2);
  u16* Whead   = (u16*)take((size_t)4096 * 768 * 2);
  float* condf = (float*)take((size_t)128 * 768 * 4);
  u16* conds   = (u16*)take((size_t)128 * 768 * 2);
  u16* xvb     = (u16*)take((size_t)368640 * 2);
  u16* xbuf    = (u16*)take((size_t)12800 * 768 * 2);   // BF16 residual stream
  u16* hbuf    = (u16*)take((size_t)12800 * 768 * 2);
  float* adab  = (float*)take((size_t)128 * (size_t)adaStride * 4);
  u16* obuf    = (u16*)take((size_t)12800 * 768 * 2);
  float* hdbuf = (float*)take((size_t)128 * 1536 * 4);
  char* big    = take((size_t)12800 * 3072 * 2);
  float* xw  = (float*)big;
  u16* qkvb  = (u16*)big;
  u16* fc1b  = (u16*)big;

  (void)hipFuncSetAttribute(reinterpret_cast<const void*>(&attn_kernel),
                            hipFuncAttributeMaxDynamicSharedMemorySize, 73728);

  // ---- weight transposes (fp32 (K,N) -> bf16 (N,K)) ----
  transpose_cast  <<<dim3(24, 1, 1),  256, 0, stream>>>(word_w, Wword, 32, 768);
  transpose_cast64<<<dim3(72, 12, 8), 256, 0, stream>>>(ada_w,  Wada,  768, 4608);
  transpose_cast64<<<dim3(36, 12, 8), 256, 0, stream>>>(qkv_w,  Wqkv,  768, 2304);
  transpose_cast64<<<dim3(12, 12, 8), 256, 0, stream>>>(proj_w, Wproj, 768, 768);
  transpose_cast64<<<dim3(48, 12, 8), 256, 0, stream>>>(fc1_w,  Wfc1,  768, 3072);
  transpose_cast64<<<dim3(12, 48, 8), 256, 0, stream>>>(fc2_w,  Wfc2,  3072, 768);
  transpose_cast64<<<dim3(24, 12, 1), 256, 0, stream>>>(hnm_w,  Whnm,  768, 1536);
  transpose_cast64<<<dim3(64, 12, 1), 256, 0, stream>>>(head_w, Whead, 768, 4096);

  // ---- prologue ----
  cond_kernel<<<384, 256, 0, stream>>>(nobs, obs_w, obs_b, condf, conds);
  cast_bf16_kernel<<<1440, 256, 0, stream>>>(xv, xvb, 368640);
  gemm_kernel<0><<<dim3(6, 90), 256, 0, stream>>>(xvb, Wword, word_b,
      nullptr, xw, nullptr, nullptr, 0, 11520, 768, 32);
  build_x_kernel<<<9600, 256, 0, stream>>>(condf, pos_start, xw, lvl_emb, pos_1LC, xbuf);

  // merged adaLN GEMM for all 8 layers (M=128, N=36864, K=768)
  if (bigAda)
    gemm64_kernel<0><<<dim3(288, 1), 256, 0, stream>>>(conds, Wada, ada_b,
        nullptr, adab, nullptr, nullptr, 0, 128, 36864, 768);

  // ---- transformer layers ----
  for (int i = 0; i < 8; ++i) {
    if (!bigAda)
      gemm64_kernel<0><<<dim3(36, 1), 256, 0, stream>>>(conds, Wada + (size_t)i * 4608 * 768,
          ada_b + (size_t)i * 4608, nullptr, adab, nullptr, nullptr, 0, 128, 4608, 768);
    float* adaL = bigAda ? adab + (size_t)i * 4608 : adab;
    // slots: 0=g1 1=g2 2=s1 3=s2 4=sh1 5=sh2
    ln_mod_kernel<<<3200, 256, 0, stream>>>(xbuf, adaL + 2 * 768, adaL + 4 * 768, adaStride, hbuf);
    gemm64_kernel<1><<<dim3(18, 100), 256, 0, stream>>>(hbuf, Wqkv + (size_t)i * 2304 * 768,
        qkv_b + (size_t)i * 2304, qkvb, nullptr, nullptr, nullptr, 0, 12800, 2304, 768);
    attn_kernel<<<1536, 448, 73728, stream>>>(qkvb, obuf);
    gemm64_kernel<3><<<dim3(6, 100), 256, 0, stream>>>(obuf, Wproj + (size_t)i * 768 * 768,
        proj_b + (size_t)i * 768, nullptr, nullptr, xbuf, adaL + 0 * 768, adaStride, 12800, 768, 768);
    ln_mod_kernel<<<3200, 256, 0, stream>>>(xbuf, adaL + 3 * 768, adaL + 5 * 768, adaStride, hbuf);
    gemm64_kernel<2><<<dim3(24, 100), 256, 0, stream>>>(hbuf, Wfc1 + (size_t)i * 3072 * 768,
        fc1_b + (size_t)i * 3072, fc1b, nullptr, nullptr, nullptr, 0, 12800, 3072, 768);
    gemm64_kernel<3><<<dim3(6, 100), 256, 0, stream>>>(fc1b, Wfc2 + (size_t)i * 768 * 3072,
        fc2_b + (size_t)i * 768, nullptr, nullptr, xbuf, adaL + 1 * 768, adaStride, 12800, 768, 3072);
  }

  // ---- head ----
  gemm_kernel<0><<<dim3(12, 1), 256, 0, stream>>>(conds, Whnm, hnm_b,
      nullptr, hdbuf, nullptr, nullptr, 0, 128, 1536, 768);
  ln_mod_kernel<<<3200, 256, 0, stream>>>(xbuf, hdbuf, hdbuf + 768, 1536, hbuf);
  gemm64_kernel<4><<<dim3(32, 100), 256, 0, stream>>>(hbuf, Whead, head_b,
      nullptr, out, nullptr, nullptr, 0, 12800, 4096, 768);
}